// Round 1
// baseline (1084.613 us; speedup 1.0000x reference)
//
#include <hip/hip_runtime.h>

typedef _Float16 h8_t __attribute__((ext_vector_type(8)));
typedef _Float16 h4_t __attribute__((ext_vector_type(4)));
typedef float f4_t __attribute__((ext_vector_type(4)));

#define MFMA16(a, b, c) __builtin_amdgcn_mfma_f32_16x16x32_f16((a), (b), (c), 0, 0, 0)

// async global->LDS DMA, 16B per lane; LDS dest must be wave-uniform base + lane*16
__device__ inline void gl_lds16(const _Float16* g, _Float16* l) {
    __builtin_amdgcn_global_load_lds(
        (const __attribute__((address_space(1))) unsigned int*)g,
        (__attribute__((address_space(3))) unsigned int*)l, 16, 0, 0);
}

// ---------------------------------------------------------------------------
// f32 -> f16 flat convert (vectorized x4) — used only for rel now
__global__ void cvt4(const float* __restrict__ in, _Float16* __restrict__ out, int n4) {
    int i = blockIdx.x * 256 + threadIdx.x;
    if (i < n4) {
        f4_t v = *(const f4_t*)(in + (size_t)i * 4);
        h4_t h;
        for (int j = 0; j < 4; ++j) h[j] = (_Float16)v[j];
        *(h4_t*)(out + (size_t)i * 4) = h;
    }
}

// ---------------------------------------------------------------------------
// W [K=1024][N=1024] f32  ->  Wt [N][K] f16   (tiled transpose)
__global__ void wtrans(const float* __restrict__ W, _Float16* __restrict__ Wt) {
    __shared__ float tile[32][33];
    int tid = threadIdx.x;
    int tx = tid & 31, ty = tid >> 5;
    int nb = blockIdx.x * 32, kb = blockIdx.y * 32;
    for (int p = 0; p < 4; ++p)
        tile[ty + p * 8][tx] = W[(size_t)(kb + ty + p * 8) * 1024 + nb + tx];
    __syncthreads();
    for (int p = 0; p < 4; ++p)
        Wt[(size_t)(nb + ty + p * 8) * 1024 + kb + tx] = (_Float16)tile[tx][ty + p * 8];
}

// ---------------------------------------------------------------------------
// Projection GEMM. A-operand read directly from f32 activations (reg-staged +
// cvt), B-operand (pre-transposed f16 weights) staged via global_load_lds.
// Out = (X @ Wt^T + bias) * scale.
// vmode==0: Out [b][h][s][64] ; vmode==1: Out [b][h][64][s] (V transposed)
__global__ __launch_bounds__(256, 2) void proj_gemm(
    const float* __restrict__ X, const _Float16* __restrict__ Wt,
    const float* __restrict__ bias, _Float16* __restrict__ Out,
    float scale, int vmode)
{
    __shared__ __align__(16) _Float16 Asm[128 * 32];
    __shared__ __align__(16) _Float16 Bsm[128 * 32];
    int tid = threadIdx.x;
    int wave = tid >> 6, lane = tid & 63;
    int l15 = lane & 15, quad = lane >> 4;
    int m0 = blockIdx.x * 128, n0 = blockIdx.y * 128;
    int wm = (wave >> 1) * 64, wn = (wave & 1) * 64;
    f4_t acc[4][4] = {};
    int f0 = wave * 128 + lane;

    for (int kt = 0; kt < 1024; kt += 32) {
        #pragma unroll
        for (int j = 0; j < 2; ++j) {
            int f = f0 + j * 64;
            int r = f >> 2, c = (f & 3) * 8;
            gl_lds16(&Wt[(size_t)(n0 + r) * 1024 + kt + c], &Bsm[f * 8]);
        }
        #pragma unroll
        for (int j = 0; j < 2; ++j) {
            int f = f0 + j * 64;
            int r = f >> 2, c = (f & 3) * 8;
            const float* xp = &X[(size_t)(m0 + r) * 1024 + kt + c];
            f4_t x0 = *(const f4_t*)xp;
            f4_t x1 = *(const f4_t*)(xp + 4);
            h8_t h;
            #pragma unroll
            for (int i = 0; i < 4; ++i) { h[i] = (_Float16)x0[i]; h[4 + i] = (_Float16)x1[i]; }
            *(h8_t*)&Asm[f * 8] = h;
        }
        __syncthreads();  // drains vmcnt(0) (B staging) + lgkm (A ds_writes)
        h8_t af[4], bf[4];
        #pragma unroll
        for (int i = 0; i < 4; ++i) af[i] = *(const h8_t*)&Asm[(wm + i * 16 + l15) * 32 + quad * 8];
        #pragma unroll
        for (int j = 0; j < 4; ++j) bf[j] = *(const h8_t*)&Bsm[(wn + j * 16 + l15) * 32 + quad * 8];
        #pragma unroll
        for (int i = 0; i < 4; ++i)
            #pragma unroll
            for (int j = 0; j < 4; ++j)
                acc[i][j] = MFMA16(af[i], bf[j], acc[i][j]);
        __syncthreads();
    }
    #pragma unroll
    for (int j = 0; j < 4; ++j) {
        int n = n0 + wn + j * 16 + l15;
        float bv = bias[n];
        int h = n >> 6, d = n & 63;
        #pragma unroll
        for (int i = 0; i < 4; ++i) {
            #pragma unroll
            for (int r = 0; r < 4; ++r) {
                int m = m0 + wm + i * 16 + quad * 4 + r;
                int bb = m >> 10, ss = m & 1023;
                float v = (acc[i][j][r] + bv) * scale;
                size_t oidx = vmode ? (((size_t)(bb * 16 + h) * 64 + d) * 1024 + ss)
                                    : (((size_t)(bb * 16 + h) * 1024 + ss) * 64 + d);
                Out[oidx] = (_Float16)v;
            }
        }
    }
}

// ---------------------------------------------------------------------------
// rel B-operand loader: f16 path (pre-converted) or f32 fallback
__device__ inline h8_t ld_rel(const _Float16* relh, const float* relf, size_t idx) {
    if (relh) return *(const h8_t*)(relh + idx);
    f4_t a = *(const f4_t*)(relf + idx);
    f4_t b = *(const f4_t*)(relf + idx + 4);
    h8_t h;
    for (int j = 0; j < 4; ++j) { h[j] = (_Float16)a[j]; h[4 + j] = (_Float16)b[j]; }
    return h;
}

// ---------------------------------------------------------------------------
// Fused attention. WG = (batch b, 16 q-rows) covering all 16 heads.
// Scores computed TRANSPOSED: D[t][q] so softmax rows live in lane dim (l15=q).
// Kh pre-scaled by 1/8; rel added unscaled (matches reference).
// This round:
//  - super-tiles of 4 k-tiles: Phase A (rel GEMM) batched over 128 keys into a
//    single R_lds buffer; barriers 32 -> 16; long barrier-free B/C stretch.
//  - P_lds eliminated: P^T fragment transpose done in-register with quad
//    shuffles (dest quad d takes pack[tm=d>>1] from src lanes ((2d)&3)*16+l15
//    and that +16).
//  - vv loads issued before the softmax VALU chain (latency hidden under it).
// LDS = 16*17*136*2 = 73984 B (dynamic), 2 WGs/CU.
__global__ __launch_bounds__(256, 2) void attn_kernel(
    const _Float16* __restrict__ Qh,   // [B][H][S][64]
    const _Float16* __restrict__ Kh,   // [B][H][S][64], pre-scaled 1/8
    const _Float16* __restrict__ Vt,   // [B][H][64][S]
    const _Float16* __restrict__ relh, // [S][S][64] f16 or nullptr
    const float* __restrict__ relf,    // [S][S][64] f32
    const int* __restrict__ mask,      // [B][S][S] int32 (nonzero = masked)
    float* __restrict__ out)           // [B][S][1024]
{
    extern __shared__ _Float16 R_lds[];  // [16 q][17 h][136 t]

    const int tid = threadIdx.x;
    const int wave = tid >> 6, lane = tid & 63;
    const int l15 = lane & 15, quad = lane >> 4;
    const int b = blockIdx.y;
    const int q0 = blockIdx.x * 16;

    // persistent B-operand fragments of Q for QK^T (B[d][q] per wave's 4 heads)
    h8_t bQ[4][2];
    #pragma unroll
    for (int gi = 0; gi < 4; ++gi) {
        int g = wave * 4 + gi;
        const _Float16* qp = Qh + ((size_t)(b * 16 + g) * 1024 + q0 + l15) * 64 + quad * 8;
        bQ[gi][0] = *(const h8_t*)qp;
        bQ[gi][1] = *(const h8_t*)(qp + 32);
    }

    f4_t acc[4][4] = {}; // [gi][dm] O^T frags: rows d, cols q
    float mst[4], lst[4];
    #pragma unroll
    for (int gi = 0; gi < 4; ++gi) { mst[gi] = -1e30f; lst[gi] = 0.0f; }

    for (int st = 0; st < 8; ++st) {
        const int t0 = st * 128;

        // ---- Phase A: rel GEMMs for 4 k-tiles, D[t][h] per owned q -> R_lds
        // bR reloaded per super-tile (L2-hot) to cap persistent VGPRs.
        h8_t bR[4][2];
        #pragma unroll
        for (int qi = 0; qi < 4; ++qi) {
            const _Float16* qp =
                Qh + ((size_t)(b * 16 + l15) * 1024 + q0 + wave * 4 + qi) * 64 + quad * 8;
            bR[qi][0] = *(const h8_t*)qp;
            bR[qi][1] = *(const h8_t*)(qp + 32);
        }
        #pragma unroll
        for (int qi = 0; qi < 4; ++qi) {
            const int q = q0 + wave * 4 + qi;
            const int ql = wave * 4 + qi;
            h8_t rv[4][2][2];  // 16 independent loads in flight
            #pragma unroll
            for (int tl = 0; tl < 4; ++tl)
                #pragma unroll
                for (int tm = 0; tm < 2; ++tm) {
                    size_t rb = ((size_t)q * 1024 + t0 + tl * 32 + tm * 16 + l15) * 64 + quad * 8;
                    rv[tl][tm][0] = ld_rel(relh, relf, rb);
                    rv[tl][tm][1] = ld_rel(relh, relf, rb + 32);
                }
            #pragma unroll
            for (int tl = 0; tl < 4; ++tl)
                #pragma unroll
                for (int tm = 0; tm < 2; ++tm) {
                    f4_t c = {0.f, 0.f, 0.f, 0.f};
                    c = MFMA16(rv[tl][tm][0], bR[qi][0], c);
                    c = MFMA16(rv[tl][tm][1], bR[qi][1], c);
                    h4_t h;
                    #pragma unroll
                    for (int r = 0; r < 4; ++r) h[r] = (_Float16)c[r];
                    *(h4_t*)&R_lds[((size_t)ql * 17 + l15) * 136 + tl * 32 + tm * 16 + quad * 4] = h;
                }
        }
        __syncthreads();  // R visible to all waves

        // ---- Phase B/C: 4 tiles, no barriers in between
        #pragma unroll
        for (int tt = 0; tt < 4; ++tt) {
            const int t = t0 + tt * 32;

            const int* mrow = &mask[((size_t)b * 1024 + q0 + l15) * 1024 + t];
            int4 mk0 = *(const int4*)(mrow + quad * 4);
            int4 mk1 = *(const int4*)(mrow + 16 + quad * 4);

            h8_t kv[4][2][2];
            #pragma unroll
            for (int gi = 0; gi < 4; ++gi) {
                const _Float16* kp =
                    Kh + ((size_t)(b * 16 + wave * 4 + gi) * 1024 + t + l15) * 64 + quad * 8;
                kv[gi][0][0] = *(const h8_t*)kp;
                kv[gi][0][1] = *(const h8_t*)(kp + 32);
                kv[gi][1][0] = *(const h8_t*)(kp + 1024);
                kv[gi][1][1] = *(const h8_t*)(kp + 1056);
            }

            // QK^T for all gi (kv dead afterwards)
            f4_t s[4][2];
            #pragma unroll
            for (int gi = 0; gi < 4; ++gi) {
                const int g = wave * 4 + gi;
                #pragma unroll
                for (int tm = 0; tm < 2; ++tm) {
                    h4_t rh = *(const h4_t*)&R_lds[((size_t)l15 * 17 + g) * 136 + tt * 32 + tm * 16 + quad * 4];
                    f4_t c;
                    #pragma unroll
                    for (int r = 0; r < 4; ++r) c[r] = (float)rh[r];
                    c = MFMA16(kv[gi][tm][0], bQ[gi][0], c);
                    c = MFMA16(kv[gi][tm][1], bQ[gi][1], c);
                    s[gi][tm] = c;
                }
            }

            // V batch issued now: latency hides under the softmax VALU chain
            h8_t vv[4][4];
            #pragma unroll
            for (int gi = 0; gi < 4; ++gi) {
                const _Float16* vp =
                    Vt + (size_t)(b * 16 + wave * 4 + gi) * 65536 + t + quad * 8;
                #pragma unroll
                for (int dm = 0; dm < 4; ++dm)
                    vv[gi][dm] = *(const h8_t*)(vp + (size_t)(dm * 16 + l15) * 1024);
            }

            int mm[8] = {mk0.x, mk0.y, mk0.z, mk0.w, mk1.x, mk1.y, mk1.z, mk1.w};

            // online softmax + in-register P^T transpose (quad shuffles)
            h8_t bp[4];
            #pragma unroll
            for (int gi = 0; gi < 4; ++gi) {
                #pragma unroll
                for (int tm = 0; tm < 2; ++tm)
                    #pragma unroll
                    for (int r = 0; r < 4; ++r)
                        if (mm[tm * 4 + r]) s[gi][tm][r] = -1e8f;

                float mx = s[gi][0][0];
                #pragma unroll
                for (int tm = 0; tm < 2; ++tm)
                    #pragma unroll
                    for (int r = 0; r < 4; ++r) mx = fmaxf(mx, s[gi][tm][r]);
                mx = fmaxf(mx, __shfl_xor(mx, 16));
                mx = fmaxf(mx, __shfl_xor(mx, 32));
                float mnew = fmaxf(mst[gi], mx);
                float alpha = __expf(mst[gi] - mnew);
                mst[gi] = mnew;
                float rs = 0.0f;
                #pragma unroll
                for (int tm = 0; tm < 2; ++tm)
                    #pragma unroll
                    for (int r = 0; r < 4; ++r) {
                        float p = __expf(s[gi][tm][r] - mnew);
                        s[gi][tm][r] = p;
                        rs += p;
                    }
                rs += __shfl_xor(rs, 16);
                rs += __shfl_xor(rs, 32);
                lst[gi] = lst[gi] * alpha + rs;
                #pragma unroll
                for (int dm = 0; dm < 4; ++dm) acc[gi][dm] *= alpha; // alpha uniform per q=l15

                // pack P to f16, then transpose across quads:
                // lane (quad,l15) holds P[t=tm*16+quad*4+r][q=l15];
                // PV B-frag needs bp[j] = P[quad*8+j][q=l15].
                union { h4_t h; unsigned u[2]; } pk0, pk1;
                #pragma unroll
                for (int r = 0; r < 4; ++r) {
                    pk0.h[r] = (_Float16)s[gi][0][r];
                    pk1.h[r] = (_Float16)s[gi][1][r];
                }
                const int src0 = ((quad & 1) << 5) + l15;  // quad (2d)&3
                const int src1 = src0 + 16;                // quad (2d)&3 + 1
                unsigned a0 = __shfl(pk0.u[0], src0), a1 = __shfl(pk0.u[1], src0);
                unsigned c0 = __shfl(pk1.u[0], src0), c1 = __shfl(pk1.u[1], src0);
                unsigned d0 = __shfl(pk0.u[0], src1), d1 = __shfl(pk0.u[1], src1);
                unsigned e0 = __shfl(pk1.u[0], src1), e1 = __shfl(pk1.u[1], src1);
                const bool hi2 = quad >= 2;                // tm = quad>>1
                union { h8_t h; unsigned u[4]; } r8;
                r8.u[0] = hi2 ? c0 : a0;
                r8.u[1] = hi2 ? c1 : a1;
                r8.u[2] = hi2 ? e0 : d0;
                r8.u[3] = hi2 ? e1 : d1;
                bp[gi] = r8.h;
            }

            // ---- PV: O^T[d][q] += V^T[d][t] * P^T[t][q]
            #pragma unroll
            for (int gi = 0; gi < 4; ++gi)
                #pragma unroll
                for (int dm = 0; dm < 4; ++dm)
                    acc[gi][dm] = MFMA16(vv[gi][dm], bp[gi], acc[gi][dm]);
        }
        __syncthreads();  // all R reads done before next Phase A overwrites
    }

    // ---- epilogue: out[b][q][g*64+d] = O^T / l
    #pragma unroll
    for (int gi = 0; gi < 4; ++gi) {
        int g = wave * 4 + gi;
        float linv = 1.0f / lst[gi];
        #pragma unroll
        for (int dm = 0; dm < 4; ++dm) {
            f4_t v = acc[gi][dm] * linv;
            float* op = out + ((size_t)b * 1024 + q0 + l15) * 1024 + g * 64 + dm * 16 + quad * 4;
            *(f4_t*)op = v;
        }
    }
}

// ---------------------------------------------------------------------------
extern "C" void kernel_launch(void* const* d_in, const int* in_sizes, int n_in,
                              void* d_out, int out_size, void* d_ws, size_t ws_size,
                              hipStream_t stream) {
    const float* q    = (const float*)d_in[0];
    const float* k    = (const float*)d_in[1];
    const float* v    = (const float*)d_in[2];
    const float* rel  = (const float*)d_in[3];
    const float* Wq   = (const float*)d_in[4];
    const float* bq   = (const float*)d_in[5];
    const float* Wk   = (const float*)d_in[6];
    const float* bk   = (const float*)d_in[7];
    const float* Wv   = (const float*)d_in[8];
    const float* bv   = (const float*)d_in[9];
    const int*   mask = (const int*)d_in[10];
    float* out = (float*)d_out;

    const size_t NEL = 8ull * 1024 * 1024;      // activation elements
    const size_t WEL = 1024ull * 1024;          // weight elements
    const size_t RELE = 1024ull * 1024 * 64;    // rel elements

    char* w = (char*)d_ws;
    size_t off = 0;
    auto alloc = [&](size_t bytes) { char* p = w + off; off += bytes; return p; };
    // No flat f16 copies of q/k/v: proj reads f32 directly. This drops the
    // workspace floor for relh from 236 MB to 188 MB.
    _Float16* Wqt = (_Float16*)alloc(WEL * 2);
    _Float16* Wkt = (_Float16*)alloc(WEL * 2);
    _Float16* Wvt = (_Float16*)alloc(WEL * 2);
    _Float16* Qh  = (_Float16*)alloc(NEL * 2);
    _Float16* Kh  = (_Float16*)alloc(NEL * 2);
    _Float16* Vth = (_Float16*)alloc(NEL * 2);
    _Float16* relh = nullptr;
    if (ws_size >= off + RELE * 2) relh = (_Float16*)alloc(RELE * 2);

    if (relh)
        cvt4<<<(int)(RELE / 4 / 256), 256, 0, stream>>>(rel, relh, (int)(RELE / 4));

    dim3 tg(32, 32);
    wtrans<<<tg, 256, 0, stream>>>(Wq, Wqt);
    wtrans<<<tg, 256, 0, stream>>>(Wk, Wkt);
    wtrans<<<tg, 256, 0, stream>>>(Wv, Wvt);

    dim3 pg(64, 8);
    proj_gemm<<<pg, 256, 0, stream>>>(q, Wqt, bq, Qh, 1.0f, 0);
    proj_gemm<<<pg, 256, 0, stream>>>(k, Wkt, bk, Kh, 0.125f, 0); // fold 1/sqrt(dk)
    proj_gemm<<<pg, 256, 0, stream>>>(v, Wvt, bv, Vth, 1.0f, 1);  // V transposed

    dim3 ag(64, 8);
    size_t shb = (size_t)16 * 17 * 136 * sizeof(_Float16); // 73984 B
    attn_kernel<<<ag, 256, shb, stream>>>(Qh, Kh, Vth, relh, rel, mask, out);
}